// Round 11
// baseline (275.303 us; speedup 1.0000x reference)
//
#include <hip/hip_runtime.h>
#include <hip/hip_bf16.h>

typedef unsigned short u16;
typedef unsigned int u32;

#define Tn 128
#define Fn 512
#define HWc (Tn*Fn)
#define EPS 1e-5f

using bf16x8 = __attribute__((ext_vector_type(8))) short;
using f32x4  = __attribute__((ext_vector_type(4))) float;

__device__ __forceinline__ float b2f(u16 x){ return __uint_as_float(((u32)x)<<16); }
__device__ __forceinline__ u16 f2b(float f){
  __hip_bfloat16 h = __float2bfloat16(f);
  return *reinterpret_cast<u16*>(&h);
}

// async global->LDS, 16B per lane
__device__ __forceinline__ void gload16(const u16* g, u16* l){
  __builtin_amdgcn_global_load_lds((const __attribute__((address_space(1))) void*)g,
                                   (__attribute__((address_space(3))) void*)l, 16, 0, 0);
}

// ---------------- zero stats ----------------
__global__ void zero_stats2(float* a, float* b){
  int i = threadIdx.x;
  if (i < 128) a[i] = 0.f;
  else if (i < 160) b[i-128] = 0.f;
}

// ---------------- zero only the padded borders of an NHWC-padded buffer ----------------
__global__ __launch_bounds__(256) void border_zero(u16* __restrict__ p, int CS){
  int b = blockIdx.y;
  u16* base = p + (long)b*130*514*CS;
  int rowN = 514*CS;
  for (int i = blockIdx.x*256 + threadIdx.x; i < rowN; i += gridDim.x*256){
    base[i] = 0;
    base[(long)129*rowN + i] = 0;
  }
  int colN = 128*CS;
  for (int i = blockIdx.x*256 + threadIdx.x; i < colN; i += gridDim.x*256){
    int row = 1 + i/CS, ch = i - (i/CS)*CS;
    base[((long)row*514 + 0)*CS + ch] = 0;
    base[((long)row*514 + 513)*CS + ch] = 0;
  }
}

// ---------------- fp32 -> bf16 weight conversion (flat) ----------------
__global__ __launch_bounds__(256) void cvt_f2b(const float* __restrict__ src, u16* __restrict__ dst){
  int i = (blockIdx.x*256 + threadIdx.x)*4;
  float4 v = *(const float4*)(src + i);
  ushort4 o;
  o.x=f2b(v.x); o.y=f2b(v.y); o.z=f2b(v.z); o.w=f2b(v.w);
  *(ushort4*)(dst + i) = o;
}

// ---------------- conv weight reorg, FRAGMENT ORDER: wr[dt][KP/32][q:4][h:2][r:16][8] ----------------
__global__ __launch_bounds__(256)
void prep_wr(const float* __restrict__ w, u16* __restrict__ wr,
             int CIN, int cs, int cof, int KP){
  int i = blockIdx.x*256 + threadIdx.x;
  int tot = 96*KP;
  if (i >= tot) return;
  int e  = i & 7;
  int r  = (i >> 3) & 15;
  int h  = (i >> 7) & 1;
  int q  = (i >> 8) & 3;
  int rest = i >> 10;
  int NK = KP >> 5;
  int ks = rest % NK, dt = rest / NK;
  int o = h*16 + r;
  int k = ks*32 + q*8 + e;
  float v = 0.f;
  int g = cof + k, df = g/cs, ch = g - df*cs;
  if (o < 24 && df < 3 && ch >= cof && ch < cof+CIN)
    v = w[((o*CIN + (ch-cof))*3 + dt)*3 + df];
  wr[i] = f2b(v);
}

// ---------------- copy x (CHW fp32) -> b72p NHWC ch48..72 AND xc24 NHWC compact ----------------
__global__ __launch_bounds__(256)
void copy_x2(const float* __restrict__ x, u16* __restrict__ b72p, u16* __restrict__ xc24){
  __shared__ u16 sh[24][520];
  int t = blockIdx.x & 127, b = blockIdx.x >> 7;
  const float* src = x + ((long)(b*24)*128 + t)*512;
  for (int c=0; c<24; c++){
    float2 v = *(const float2*)(src + (long)c*65536 + threadIdx.x*2);
    sh[c][threadIdx.x*2]   = f2b(v.x);
    sh[c][threadIdx.x*2+1] = f2b(v.y);
  }
  __syncthreads();
  long r72 = ((long)(b*130 + t+1))*514*72;
  long r24 = ((long)(b*130 + t+1))*514*24;
  for (int i = threadIdx.x; i < 1536; i += 256){
    int f = i/3, c0 = (i%3)*8;
    union {int4 q; u16 u[8];} o;
    #pragma unroll
    for (int j=0;j<8;j++) o.u[j] = sh[c0+j][f];
    *(int4*)(b72p + r72 + (long)(f+1)*72 + 48 + c0) = o.q;
    *(int4*)(xc24 + r24 + (long)(f+1)*24 + c0) = o.q;
  }
}

// ---------------- MFMA implicit-GEMM 3x3 conv v6 (round-8 known-good) ----------------
template<int KP, int CS>
__global__ __launch_bounds__(256)
void conv_mfma(const u16* __restrict__ X, int coff, const u16* __restrict__ WR,
               const float* __restrict__ bias, u16* __restrict__ Y,
               float* __restrict__ raw){
  constexpr int NK = KP/32;
  __shared__ u16 WS[3*32*KP];
  __shared__ float ssum[4][32], ssq[4][32];
  __shared__ float g24s[24], g24q[24];
  __shared__ __align__(16) u16 Ysh[128*24];
  int bid = (blockIdx.x & 7)*64 + (blockIdx.x >> 3);   // grid 512, chunk 64
  int b = bid >> 7, t = bid & 127;
  int tid = threadIdx.x, wid = tid >> 6, l = tid & 63;
  int r = l & 15, q = l >> 4;

  for (int i = tid*8; i < 3*32*KP; i += 2048)
    *(int4*)(WS + i) = *(const int4*)(WR + i);

  float bv0 = bias[r];
  float bv1 = (r < 8) ? bias[16+r] : 0.f;
  float s0=0,q0=0,s1=0,q1=0;
  __syncthreads();

  #pragma unroll
  for (int fi=0; fi<4; fi++){
    int f0w = fi*128 + wid*32;
    f32x4 acc[2][2] = {};
    #pragma unroll
    for (int dt=0; dt<3; dt++){
      const u16* Ab = X + ((long)((b*130 + t+dt)*514 + f0w + r))*CS + coff + q*8;
      bf16x8 a[2][NK];
      #pragma unroll
      for (int ks=0; ks<NK; ks++){
        a[0][ks] = *(const bf16x8*)(Ab + ks*32);
        a[1][ks] = *(const bf16x8*)(Ab + (long)16*CS + ks*32);
      }
      #pragma unroll
      for (int ks=0; ks<NK; ks++){
        const u16* Bb = WS + ((dt*NK + ks)*4 + q)*256 + r*8;
        bf16x8 b0 = *(const bf16x8*)(Bb);
        bf16x8 b1 = *(const bf16x8*)(Bb + 128);
        acc[0][0] = __builtin_amdgcn_mfma_f32_16x16x32_bf16(a[0][ks],b0,acc[0][0],0,0,0);
        acc[0][1] = __builtin_amdgcn_mfma_f32_16x16x32_bf16(a[0][ks],b1,acc[0][1],0,0,0);
        acc[1][0] = __builtin_amdgcn_mfma_f32_16x16x32_bf16(a[1][ks],b0,acc[1][0],0,0,0);
        acc[1][1] = __builtin_amdgcn_mfma_f32_16x16x32_bf16(a[1][ks],b1,acc[1][1],0,0,0);
      }
    }
    #pragma unroll
    for (int m=0;m<2;m++){
      #pragma unroll
      for (int j=0;j<4;j++){
        acc[m][0][j] += bv0; acc[m][1][j] += bv1;
        s0 += acc[m][0][j]; q0 += acc[m][0][j]*acc[m][0][j];
        s1 += acc[m][1][j]; q1 += acc[m][1][j]*acc[m][1][j];
      }
    }
    __syncthreads();
    #pragma unroll
    for (int m=0;m<2;m++){
      int fr = wid*32 + m*16 + q*4;
      #pragma unroll
      for (int j=0;j<4;j++){
        Ysh[(fr+j)*24 + r] = f2b(acc[m][0][j]);
        if (r < 8) Ysh[(fr+j)*24 + 16 + r] = f2b(acc[m][1][j]);
      }
    }
    __syncthreads();
    long Yb = ((long)((b*128 + t)*512) + fi*128)*24;
    const int4* sp = (const int4*)Ysh;
    for (int i = tid; i < 384; i += 256)
      *(int4*)(Y + Yb + (long)i*8) = sp[i];
  }

  #pragma unroll
  for (int off=16; off<=32; off<<=1){
    s0 += __shfl_xor(s0, off, 64); q0 += __shfl_xor(q0, off, 64);
    s1 += __shfl_xor(s1, off, 64); q1 += __shfl_xor(q1, off, 64);
  }
  if (q == 0){
    ssum[wid][r] = s0;     ssq[wid][r] = q0;
    ssum[wid][16+r] = s1;  ssq[wid][16+r] = q1;
  }
  __syncthreads();
  if (tid < 24){
    g24s[tid] = ssum[0][tid]+ssum[1][tid]+ssum[2][tid]+ssum[3][tid];
    g24q[tid] = ssq[0][tid]+ssq[1][tid]+ssq[2][tid]+ssq[3][tid];
  }
  __syncthreads();
  if (tid < 4){
    float as=0, aq=0;
    #pragma unroll
    for (int j=0;j<6;j++){ as += g24s[tid*6+j]; aq += g24q[tid*6+j]; }
    atomicAdd(&raw[b*4+tid], as);
    atomicAdd(&raw[16+b*4+tid], aq);
  }
}

// ---------------- finalize: raw stats -> per-(b,c) scale/offset tables ----------------
__global__ void finalize_scoff(const float* __restrict__ raw, const float* __restrict__ gw,
                               const float* __restrict__ gb, float invN,
                               float* __restrict__ scA, float* __restrict__ scB){
  int i = threadIdx.x;
  if (i < 96){
    int b = i/24, c = i%24, g = b*4 + c/6;
    float m = raw[g]*invN;
    float var = raw[16+g]*invN - m*m;
    float is = rsqrtf(var + EPS);
    float sc = is*gw[c];
    scA[i] = sc;
    scB[i] = gb[c] - m*sc;
  }
}

// ---------------- normalize+relu: Y NHWC -> b72p channel slice ----------------
__global__ __launch_bounds__(256)
void norm_relu_nhwc(const u16* __restrict__ Y, u16* __restrict__ dst, int coff,
                    const float* __restrict__ scA, const float* __restrict__ scB){
  long e = ((long)blockIdx.x*256 + threadIdx.x)*8;
  int c0 = (int)(e % 24);
  long fi = e / 24;
  int f = (int)(fi & 511);
  int bt = (int)(fi >> 9); int t = bt & 127, b = bt >> 7;
  float4 sa0 = *(const float4*)(scA + b*24 + c0);
  float4 sa1 = *(const float4*)(scA + b*24 + c0 + 4);
  float4 sb0 = *(const float4*)(scB + b*24 + c0);
  float4 sb1 = *(const float4*)(scB + b*24 + c0 + 4);
  float A[8]  = {sa0.x,sa0.y,sa0.z,sa0.w,sa1.x,sa1.y,sa1.z,sa1.w};
  float Bv[8] = {sb0.x,sb0.y,sb0.z,sb0.w,sb1.x,sb1.y,sb1.z,sb1.w};
  union {int4 q; u16 u[8];} pk; pk.q = *(const int4*)(Y + e);
  union {int4 q; u16 u[8];} o;
  #pragma unroll
  for (int j=0;j<8;j++){ float v = b2f(pk.u[j])*A[j] + Bv[j]; o.u[j] = f2b(v>0.f?v:0.f); }
  *(int4*)(dst + ((long)(b*130 + t+1)*514 + (f+1))*72 + coff + c0) = o.q;
}

// ---------------- normalize+relu + NHWC->CHW transpose (conv2 output -> xr) ----------------
__global__ __launch_bounds__(256)
void norm_relu_chw(const u16* __restrict__ Y, u16* __restrict__ xr,
                   const float* __restrict__ scA, const float* __restrict__ scB){
  __shared__ u16 sh[24][520];
  __shared__ float sA[24], sB[24];
  int t = blockIdx.x & 127, b = blockIdx.x >> 7;
  if (threadIdx.x < 24){ sA[threadIdx.x] = scA[b*24+threadIdx.x]; sB[threadIdx.x] = scB[b*24+threadIdx.x]; }
  __syncthreads();
  const u16* src = Y + ((long)(b*128+t))*12288;
  for (int i = threadIdx.x; i < 1536; i += 256){
    int e = i*8; int c0 = e % 24; int f = e / 24;
    union {int4 q; u16 u[8];} pk; pk.q = *(const int4*)(src + e);
    #pragma unroll
    for (int j=0;j<8;j++){
      float v = b2f(pk.u[j])*sA[c0+j] + sB[c0+j];
      sh[c0+j][f] = f2b(v>0.f?v:0.f);
    }
  }
  __syncthreads();
  for (int i = threadIdx.x; i < 1536; i += 256){
    int c = i >> 6, fq = (i & 63)*8;
    union {int4 q; u16 u[8];} o;
    #pragma unroll
    for (int j=0;j<8;j++) o.u[j] = sh[c][fq+j];
    *(int4*)(xr + ((long)((b*24+c)*128 + t))*512 + fq) = o.q;
  }
}

// ---------------- elementwise normalize+relu on CHW rows (h1, rowlen 192) ----------------
__global__ __launch_bounds__(256)
void norm_chw(u16* __restrict__ h, const float* __restrict__ scA, const float* __restrict__ scB){
  long e = ((long)blockIdx.x*256 + threadIdx.x)*8;
  long row = e / 192;
  int c = (int)((row >> 7) % 24);
  int b = (int)(row / 3072);
  float sc = scA[b*24+c], off = scB[b*24+c];
  union {int4 q; u16 u[8];} pk; pk.q = *(const int4*)(h + e);
  #pragma unroll
  for (int j=0;j<8;j++){ float v = b2f(pk.u[j])*sc + off; pk.u[j] = f2b(v>0.f?v:0.f); }
  *(int4*)(h + e) = pk.q;
}

// ---------------- gemm1: LDS-staged pipelined GEMM (K=512), store + GN stats ----------------
template<int NF, bool STORE>
__global__ __launch_bounds__(256)
void gemm_lds(const u16* __restrict__ A, const u16* __restrict__ Bt, u16* __restrict__ C,
              int N, int K, int NBX, float* __restrict__ raw){
  constexpr int BN = NF*32;
  constexpr int BNP = BN + 8;
  constexpr int ABUF = 128*32;
  constexpr int BBUF = BN*32;
  __shared__ __align__(16) u16 SH[3*(ABUF+BBUF)];
  u16* Asb = SH;
  u16* Bsb = SH + 3*ABUF;
  int tid = threadIdx.x, wid = tid >> 6, l = tid & 63;
  int r = l & 15, q = l >> 4;
  int wr = wid >> 1, wc = wid & 1;
  int chunk = gridDim.x >> 3;
  int lin = (blockIdx.x & 7)*chunk + (blockIdx.x >> 3);
  int bx = lin % NBX, by = lin / NBX;
  long m0 = (long)by*128;
  int n0 = bx*BN;

  int arow[2], ach[2], aslot[2];
  #pragma unroll
  for (int j=0;j<2;j++){
    int idx = (wid*2+j)*64 + l;
    aslot[j] = idx*8;
    arow[j]  = ((idx>>6)<<4) | (idx & 15);
    ach[j]   = ((idx>>4) & 3)*8;
  }
  int brow[NF/2], bch[NF/2], bslot[NF/2];
  #pragma unroll
  for (int j=0;j<NF/2;j++){
    int idx = (wid*(NF/2)+j)*64 + l;
    bslot[j] = idx*8;
    brow[j]  = ((idx>>6)<<4) | (idx & 15);
    bch[j]   = ((idx>>4) & 3)*8;
  }

  f32x4 acc[4][NF];
  #pragma unroll
  for (int mf=0;mf<4;mf++)
    #pragma unroll
    for (int nf=0;nf<NF;nf++) acc[mf][nf] = (f32x4){0.f,0.f,0.f,0.f};

  int nt = K >> 5;
  #pragma unroll
  for (int j=0;j<2;j++)    gload16(A  + (m0+arow[j])*K + ach[j], Asb + aslot[j]);
  #pragma unroll
  for (int j=0;j<NF/2;j++) gload16(Bt + (long)(n0+brow[j])*K + bch[j], Bsb + bslot[j]);
  #pragma unroll
  for (int j=0;j<2;j++)    gload16(A  + (m0+arow[j])*K + 32 + ach[j], Asb + ABUF + aslot[j]);
  #pragma unroll
  for (int j=0;j<NF/2;j++) gload16(Bt + (long)(n0+brow[j])*K + 32 + bch[j], Bsb + BBUF + bslot[j]);

  int c0 = 0;
  for (int kt=0; kt<nt; kt++){
    if constexpr (NF==4) asm volatile("s_waitcnt vmcnt(4)" ::: "memory");
    else                 asm volatile("s_waitcnt vmcnt(3)" ::: "memory");
    __builtin_amdgcn_s_barrier();
    __builtin_amdgcn_sched_barrier(0);
    if (kt+2 < nt){
      int c2 = c0+2; if (c2>=3) c2-=3;
      int ko = (kt+2)*32;
      #pragma unroll
      for (int j=0;j<2;j++)    gload16(A  + (m0+arow[j])*K + ko + ach[j], Asb + c2*ABUF + aslot[j]);
      #pragma unroll
      for (int j=0;j<NF/2;j++) gload16(Bt + (long)(n0+brow[j])*K + ko + bch[j], Bsb + c2*BBUF + bslot[j]);
    }
    const u16* Ac = Asb + c0*ABUF;
    const u16* Bc = Bsb + c0*BBUF;
    bf16x8 af[4], bfv[NF];
    #pragma unroll
    for (int mf=0;mf<4;mf++) af[mf]  = *(const bf16x8*)(Ac + (((wr*4+mf)*4 + q)*16 + r)*8);
    #pragma unroll
    for (int nf=0;nf<NF;nf++) bfv[nf] = *(const bf16x8*)(Bc + (((wc*NF+nf)*4 + q)*16 + r)*8);
    #pragma unroll
    for (int mf=0;mf<4;mf++)
      #pragma unroll
      for (int nf=0;nf<NF;nf++)
        acc[mf][nf] = __builtin_amdgcn_mfma_f32_16x16x32_bf16(af[mf], bfv[nf], acc[mf][nf], 0,0,0);
    c0 = (c0+1==3) ? 0 : c0+1;
  }

  float s=0.f, ss=0.f;
  #pragma unroll
  for (int mf=0;mf<4;mf++)
    #pragma unroll
    for (int nf=0;nf<NF;nf++)
      #pragma unroll
      for (int j=0;j<4;j++){ float v = acc[mf][nf][j]; s += v; ss += v*v; }
  #pragma unroll
  for (int off=32; off>0; off>>=1){ s += __shfl_down(s,off,64); ss += __shfl_down(ss,off,64); }
  __shared__ float rs[4], rss[4];
  if (l==0){ rs[wid]=s; rss[wid]=ss; }
  __syncthreads();
  if (tid==0){
    int bc = (int)(m0 >> 7);
    int g = (bc/24)*4 + (bc%24)/6;
    atomicAdd(&raw[g],    rs[0]+rs[1]+rs[2]+rs[3]);
    atomicAdd(&raw[16+g], rss[0]+rss[1]+rss[2]+rss[3]);
  }

  if constexpr (STORE){
    #pragma unroll
    for (int mf=0;mf<4;mf++){
      int row = wr*64 + mf*16 + q*4;
      #pragma unroll
      for (int nf=0;nf<NF;nf++){
        int col = wc*(NF*16) + nf*16 + r;
        #pragma unroll
        for (int j=0;j<4;j++)
          SH[(row+j)*BNP + col] = f2b(acc[mf][nf][j]);
      }
    }
    __syncthreads();
    constexpr int RPT = BN/16;
    #pragma unroll
    for (int k=0;k<RPT;k++){
      int j = tid + k*256;
      int row = j / (BN/8), col8 = (j % (BN/8))*8;
      *(int4*)(C + (m0+row)*N + n0 + col8) = *(const int4*)(SH + row*BNP + col8);
    }
  }
}

// ---------------- gemm2 pass A: full-K (192) one-shot stage, stats only ----------------
// Tile 128x128, grid 2304 = 24(N) x 96(M), XCD-chunked. LDS = 96KB, 1 block/CU.
__global__ __launch_bounds__(256)
void gemm2_stats(const u16* __restrict__ A, const u16* __restrict__ Bt,
                 float* __restrict__ raw){
  __shared__ __align__(16) u16 As[128*192];
  __shared__ __align__(16) u16 Bs[128*192];
  __shared__ float rs[4], rss[4];
  const int K = 192;
  int tid = threadIdx.x, wid = tid >> 6, l = tid & 63;
  int r = l & 15, q = l >> 4;
  int wr = wid >> 1, wc = wid & 1;
  int lin = (blockIdx.x & 7)*288 + (blockIdx.x >> 3);
  int bx = lin % 24, by = lin / 24;
  long m0 = (long)by*128;
  long n0 = (long)bx*128;

  // stage all of K in two phases (ks 0..2, then 3..5); fragment-ordered slots
  #pragma unroll
  for (int ph=0; ph<2; ph++){
    #pragma unroll
    for (int k3=0; k3<3; k3++){
      int ks = ph*3 + k3;
      int kk = ks*32 + q*8;
      #pragma unroll
      for (int rh=0; rh<2; rh++){
        int hi = wid*2 + rh;
        int e = hi*6 + ks;
        gload16(A + (m0 + hi*16 + r)*K + kk, As + e*512 + l*8);
      }
      #pragma unroll
      for (int rh=0; rh<2; rh++){
        int hi = wid*2 + rh;
        int e = hi*6 + ks;
        gload16(Bt + (n0 + hi*16 + r)*K + kk, Bs + e*512 + l*8);
      }
    }
  }

  f32x4 acc[4][4];
  #pragma unroll
  for (int mf=0;mf<4;mf++)
    #pragma unroll
    for (int nf=0;nf<4;nf++) acc[mf][nf] = (f32x4){0.f,0.f,0.f,0.f};

  asm volatile("s_waitcnt vmcnt(12)" ::: "memory");   // phase0 (oldest 12) landed
  __builtin_amdgcn_s_barrier();
  __builtin_amdgcn_sched_barrier(0);
  #pragma unroll
  for (int ks=0; ks<3; ks++){
    bf16x8 af[4], bfv[4];
    #pragma unroll
    for (int mf=0;mf<4;mf++) af[mf]  = *(const bf16x8*)(As + (((wr*4+mf)*6 + ks)*64 + q*16 + r)*8);
    #pragma unroll
    for (int nf=0;nf<4;nf++) bfv[nf] = *(const bf16x8*)(Bs + (((wc*4+nf)*6 + ks)*64 + q*16 + r)*8);
    #pragma unroll
    for (int mf=0;mf<4;mf++)
      #pragma unroll
      for (int nf=0;nf<4;nf++)
        acc[mf][nf] = __builtin_amdgcn_mfma_f32_16x16x32_bf16(af[mf], bfv[nf], acc[mf][nf], 0,0,0);
  }
  asm volatile("s_waitcnt vmcnt(0)" ::: "memory");
  __builtin_amdgcn_s_barrier();
  __builtin_amdgcn_sched_barrier(0);
  #pragma unroll
  for (int ks=3; ks<6; ks++){
    bf16x8 af[4], bfv[4];
    #pragma unroll
    for (int mf=0;mf<4;mf++) af[mf]  = *(const bf16x8*)(As + (((wr*4+mf)*6 + ks)*64 + q*16 + r)*8);
    #pragma unroll
    for (int nf=0;nf<4;nf++) bfv[nf] = *(const bf16x8*)(Bs + (((wc*4+nf)*6 + ks)*64 + q*16 + r)*8);
    #pragma unroll
    for (int mf=0;mf<4;mf++)
      #pragma unroll
      for (int nf=0;nf<4;nf++)
        acc[mf][nf] = __builtin_amdgcn_mfma_f32_16x16x32_bf16(af[mf], bfv[nf], acc[mf][nf], 0,0,0);
  }

  float s=0.f, ss=0.f;
  #pragma unroll
  for (int mf=0;mf<4;mf++)
    #pragma unroll
    for (int nf=0;nf<4;nf++)
      #pragma unroll
      for (int j=0;j<4;j++){ float v = acc[mf][nf][j]; s += v; ss += v*v; }
  #pragma unroll
  for (int off=32; off>0; off>>=1){ s += __shfl_down(s,off,64); ss += __shfl_down(ss,off,64); }
  if (l==0){ rs[wid]=s; rss[wid]=ss; }
  __syncthreads();
  if (tid==0){
    int bc = (int)(m0 >> 7);
    int g = (bc/24)*4 + (bc%24)/6;
    atomicAdd(&raw[g],    rs[0]+rs[1]+rs[2]+rs[3]);
    atomicAdd(&raw[16+g], rss[0]+rss[1]+rss[2]+rss[3]);
  }
}

// ---------------- gemm2 pass B: full-K stage, fused GN2+ReLU+att-mix+residual -> out ----------------
// Tile 128x192 (32f x 6n), grid 1536 = 16(N) x 96(M), XCD-chunked. LDS ~120KB, 1 block/CU.
__global__ __launch_bounds__(256)
void gemm2_final(const u16* __restrict__ A, const u16* __restrict__ Bt,
                 const u16* __restrict__ xr, const float* __restrict__ scA,
                 const float* __restrict__ scB, const float* __restrict__ att,
                 float* __restrict__ out){
  __shared__ __align__(16) u16 SH[128*192 + 192*192];   // As | Bs; reused for repack
  __shared__ float att_s[6];
  u16* As = SH;
  u16* Bs = SH + 128*192;
  const int K = 192;
  int tid = threadIdx.x, wid = tid >> 6, l = tid & 63;
  int r = l & 15, q = l >> 4;
  int wr = wid >> 1, wc = wid & 1;
  int lin = (blockIdx.x & 7)*192 + (blockIdx.x >> 3);
  int bx = lin & 15, by = lin >> 4;
  long m0 = (long)by*128;
  long n0 = (long)bx*192;
  int b = by/24;
  float sc  = scA[by];
  float off = scB[by];
  if (tid < 6) att_s[tid] = att[b*6+tid];

  #pragma unroll
  for (int ph=0; ph<2; ph++){
    #pragma unroll
    for (int k3=0; k3<3; k3++){
      int ks = ph*3 + k3;
      int kk = ks*32 + q*8;
      #pragma unroll
      for (int rh=0; rh<2; rh++){
        int hi = wid*2 + rh;
        int e = hi*6 + ks;
        gload16(A + (m0 + hi*16 + r)*K + kk, As + e*512 + l*8);
      }
      #pragma unroll
      for (int rh=0; rh<3; rh++){
        int hi = wid*3 + rh;
        int e = hi*6 + ks;
        gload16(Bt + (n0 + hi*16 + r)*K + kk, Bs + e*512 + l*8);
      }
    }
  }

  f32x4 acc[4][6];
  #pragma unroll
  for (int mf=0;mf<4;mf++)
    #pragma unroll
    for (int nf=0;nf<6;nf++) acc[mf][nf] = (f32x4){0.f,0.f,0.f,0.f};

  asm volatile("s_waitcnt vmcnt(15)" ::: "memory");   // phase0 (oldest 15) landed
  __builtin_amdgcn_s_barrier();
  __builtin_amdgcn_sched_barrier(0);
  #pragma unroll
  for (int ks=0; ks<3; ks++){
    bf16x8 af[4], bfv[6];
    #pragma unroll
    for (int mf=0;mf<4;mf++) af[mf]  = *(const bf16x8*)(As + (((wr*4+mf)*6 + ks)*64 + q*16 + r)*8);
    #pragma unroll
    for (int nf=0;nf<6;nf++) bfv[nf] = *(const bf16x8*)(Bs + (((wc*6+nf)*6 + ks)*64 + q*16 + r)*8);
    #pragma unroll
    for (int mf=0;mf<4;mf++)
      #pragma unroll
      for (int nf=0;nf<6;nf++)
        acc[mf][nf] = __builtin_amdgcn_mfma_f32_16x16x32_bf16(af[mf], bfv[nf], acc[mf][nf], 0,0,0);
  }
  asm volatile("s_waitcnt vmcnt(0)" ::: "memory");
  __builtin_amdgcn_s_barrier();
  __builtin_amdgcn_sched_barrier(0);
  #pragma unroll
  for (int ks=3; ks<6; ks++){
    bf16x8 af[4], bfv[6];
    #pragma unroll
    for (int mf=0;mf<4;mf++) af[mf]  = *(const bf16x8*)(As + (((wr*4+mf)*6 + ks)*64 + q*16 + r)*8);
    #pragma unroll
    for (int nf=0;nf<6;nf++) bfv[nf] = *(const bf16x8*)(Bs + (((wc*6+nf)*6 + ks)*64 + q*16 + r)*8);
    #pragma unroll
    for (int mf=0;mf<4;mf++)
      #pragma unroll
      for (int nf=0;nf<6;nf++)
        acc[mf][nf] = __builtin_amdgcn_mfma_f32_16x16x32_bf16(af[mf], bfv[nf], acc[mf][nf], 0,0,0);
  }
  __syncthreads();     // all reads of As/Bs done -> SH reusable

  // normalize + relu + att-weight, scatter to SH[row][col] (stride 200)
  #pragma unroll
  for (int mf=0;mf<4;mf++){
    int row = wr*64 + mf*16 + q*4;
    #pragma unroll
    for (int nf=0;nf<6;nf++){
      int col = wc*96 + nf*16 + r;
      float aw = att_s[col % 6];
      #pragma unroll
      for (int j=0;j<4;j++){
        float v = acc[mf][nf][j]*sc + off;
        v = v > 0.f ? v : 0.f;
        SH[(row+j)*200 + col] = f2b(v*aw);
      }
    }
  }
  __syncthreads();

  // sum 6 experts per f, add residual, write fp32 out
  int row = tid >> 1, fh = (tid & 1)*16;
  int f0 = bx*32 + fh;
  long rg = m0 + row;
  union { int4 v[12]; u16 u[96]; } pb;
  const int4* rp = (const int4*)(SH + row*200 + fh*6);
  #pragma unroll
  for (int k=0;k<12;k++) pb.v[k] = rp[k];
  union { int4 v[2]; u16 u[16]; } xv;
  xv.v[0] = *(const int4*)(xr + rg*512 + f0);
  xv.v[1] = *(const int4*)(xr + rg*512 + f0 + 8);
  float4 ov[4];
  #pragma unroll
  for (int k=0;k<16;k++){
    float sum = 0.f;
    #pragma unroll
    for (int n=0;n<6;n++) sum += b2f(pb.u[k*6+n]);
    ((float*)ov)[k] = b2f(xv.u[k]) + sum;
  }
  #pragma unroll
  for (int k=0;k<4;k++)
    *(float4*)(out + rg*512 + f0 + k*4) = ov[k];
}

// ---------------- attention: att[4][6] (fp32) ----------------
__global__ void attention_kernel(const float* __restrict__ c, const float* __restrict__ wq,
                                 const float* __restrict__ bq, const float* __restrict__ keys,
                                 float* __restrict__ att){
  __shared__ float q[4][32];
  __shared__ float s[4][6];
  int t = threadIdx.x;
  if (t < 128){
    int b = t >> 5, k = t & 31;
    float a = bq[k];
    for (int j=0;j<32;j++) a += c[b*32+j] * wq[k*32+j];
    q[b][k] = a;
  }
  __syncthreads();
  if (t < 24){
    int b = t/6, n = t%6;
    float a = 0.f;
    for (int k=0;k<32;k++) a += q[b][k]*keys[k*6+n];
    s[b][n] = a * 0.17677669529663689f;
  }
  __syncthreads();
  if (t < 4){
    float mx = -1e30f;
    for (int n=0;n<6;n++) mx = fmaxf(mx, s[t][n]);
    float e[6], sm=0.f;
    for (int n=0;n<6;n++){ e[n]=expf(s[t][n]-mx); sm+=e[n]; }
    for (int n=0;n<6;n++) att[t*6+n] = e[n]/sm;
  }
}

extern "C" void kernel_launch(void* const* d_in, const int* in_sizes, int n_in,
                              void* d_out, int out_size, void* d_ws, size_t ws_size,
                              hipStream_t stream){
  const float* x   = (const float*)d_in[0];
  const float* c   = (const float*)d_in[1];
  const float* cw0 = (const float*)d_in[2];  const float* cb0 = (const float*)d_in[3];
  const float* gw0 = (const float*)d_in[4];  const float* gb0 = (const float*)d_in[5];
  const float* cw1 = (const float*)d_in[6];  const float* cb1 = (const float*)d_in[7];
  const float* gw1 = (const float*)d_in[8];  const float* gb1 = (const float*)d_in[9];
  const float* cw2 = (const float*)d_in[10]; const float* cb2 = (const float*)d_in[11];
  const float* gw2 = (const float*)d_in[12]; const float* gb2 = (const float*)d_in[13];
  const float* tw1 = (const float*)d_in[14]; const float* tg1w= (const float*)d_in[15]; const float* tg1b=(const float*)d_in[16];
  const float* tw2 = (const float*)d_in[17]; const float* tg2w= (const float*)d_in[18]; const float* tg2b=(const float*)d_in[19];
  const float* wqp = (const float*)d_in[20]; const float* bqp = (const float*)d_in[21]; const float* keys=(const float*)d_in[22];

  char* ws = (char*)d_ws;
  u16*   xr     = (u16*)(ws + 0);               // 12,582,912 B  [12288,512] bf16 CHW
  u16*   h1     = (u16*)(ws + 12582912);        //  4,718,592 B  [12288,192]
  u16*   tw1b   = (u16*)(ws + 17301504);        //    196,608 B
  u16*   tw2b   = (u16*)(ws + 17498112);        //  1,179,648 B
  float* stats5 = (float*)(ws + 18677760);      //        128 B
  float* scoff5 = (float*)(ws + 18677888);      //        768 B
  float* att    = (float*)(ws + 18678656);      //        128 B
  // ---- conv-phase span ----
  u16*   Y      = (u16*)(ws + 18680832);        // 12,582,912 B  NHWC conv out [4,128,512,24]
  u16*   b72p   = (u16*)(ws + 31263744);        // 38,488,320 B  NHWC padded [4,130,514,72]
  u16*   xc24   = (u16*)(ws + 69752064);        // 12,829,440 B (+256 slack) NHWC padded [4,130,514,24]
  float* stats14= (float*)(ws + 82581760);      //        512 B
  float* scoff14= (float*)(ws + 82582272);      //      3,072 B
  u16*   wr0    = (u16*)(ws + 82585344);        //     18,432 B
  u16*   wr1    = (u16*)(ws + 82603776);        //     36,864 B
  u16*   wr2    = (u16*)(ws + 82640640);        //     43,008 B

  border_zero<<<dim3(32,4),256,0,stream>>>(b72p, 72);
  border_zero<<<dim3(16,4),256,0,stream>>>(xc24, 24);
  zero_stats2<<<1,256,0,stream>>>(stats14, stats5);

  prep_wr<<<36,256,0,stream>>>(cw0, wr0, 24, 24, 0, 96);
  prep_wr<<<72,256,0,stream>>>(cw1, wr1, 48, 72, 24, 192);
  prep_wr<<<84,256,0,stream>>>(cw2, wr2, 72, 72, 0, 224);
  cvt_f2b<<<96,256,0,stream>>>(tw1, tw1b);
  cvt_f2b<<<576,256,0,stream>>>(tw2, tw2b);
  copy_x2<<<512,256,0,stream>>>(x, b72p, xc24);
  attention_kernel<<<1,128,0,stream>>>(c, wqp, bqp, keys, att);

  // ---- conv block 0 ----
  conv_mfma<96,24><<<512,256,0,stream>>>(xc24, 0, wr0, cb0, Y, stats14+0);
  finalize_scoff<<<1,96,0,stream>>>(stats14+0, gw0, gb0, 1.f/393216.f, scoff14+0, scoff14+96);
  norm_relu_nhwc<<<3072,256,0,stream>>>(Y, b72p, 24, scoff14+0, scoff14+96);

  // ---- conv block 1 ----
  conv_mfma<192,72><<<512,256,0,stream>>>(b72p, 24, wr1, cb1, Y, stats14+32);
  finalize_scoff<<<1,96,0,stream>>>(stats14+32, gw1, gb1, 1.f/393216.f, scoff14+192, scoff14+288);
  norm_relu_nhwc<<<3072,256,0,stream>>>(Y, b72p, 0, scoff14+192, scoff14+288);

  // ---- conv block 2 -> xr (CHW) ----
  conv_mfma<224,72><<<512,256,0,stream>>>(b72p, 0, wr2, cb2, Y, stats14+64);
  finalize_scoff<<<1,96,0,stream>>>(stats14+64, gw2, gb2, 1.f/393216.f, scoff14+384, scoff14+480);
  norm_relu_chw<<<512,256,0,stream>>>(Y, xr, scoff14+384, scoff14+480);

  // ---- TDF: gemm1 (12288x192x512) + GN + relu ----
  gemm_lds<2,true><<<288,256,0,stream>>>(xr, tw1b, h1, 192, 512, 3, stats14+96);
  finalize_scoff<<<1,96,0,stream>>>(stats14+96, tg1w, tg1b, 1.f/147456.f, scoff14+576, scoff14+672);
  norm_chw<<<1152,256,0,stream>>>(h1, scoff14+576, scoff14+672);

  // ---- TDF gemm2 pass A: full-K one-shot, stats only ----
  gemm2_stats<<<2304,256,0,stream>>>(h1, tw2b, stats5);
  finalize_scoff<<<1,96,0,stream>>>(stats5, tg2w, tg2b, 1.f/2359296.f, scoff5, scoff5+96);

  // ---- TDF gemm2 pass B: full-K one-shot + fused GN2/ReLU/att-mix/residual -> out ----
  gemm2_final<<<1536,256,0,stream>>>(h1, tw2b, xr, scoff5, scoff5+96, att, (float*)d_out);
}

// Round 12
// 245.186 us; speedup vs baseline: 1.1228x; 1.1228x over previous
//
#include <hip/hip_runtime.h>
#include <hip/hip_bf16.h>

typedef unsigned short u16;
typedef unsigned int u32;

#define Tn 128
#define Fn 512
#define HWc (Tn*Fn)
#define EPS 1e-5f

using bf16x8 = __attribute__((ext_vector_type(8))) short;
using f32x4  = __attribute__((ext_vector_type(4))) float;

__device__ __forceinline__ float b2f(u16 x){ return __uint_as_float(((u32)x)<<16); }
__device__ __forceinline__ u16 f2b(float f){
  __hip_bfloat16 h = __float2bfloat16(f);
  return *reinterpret_cast<u16*>(&h);
}

// async global->LDS, 16B per lane
__device__ __forceinline__ void gload16(const u16* g, u16* l){
  __builtin_amdgcn_global_load_lds((const __attribute__((address_space(1))) void*)g,
                                   (__attribute__((address_space(3))) void*)l, 16, 0, 0);
}

// ---------------- zero stats ----------------
__global__ void zero_stats2(float* a, float* b){
  int i = threadIdx.x;
  if (i < 128) a[i] = 0.f;
  else if (i < 160) b[i-128] = 0.f;
}

// ---------------- zero only the padded borders of an NHWC-padded buffer ----------------
__global__ __launch_bounds__(256) void border_zero(u16* __restrict__ p, int CS){
  int b = blockIdx.y;
  u16* base = p + (long)b*130*514*CS;
  int rowN = 514*CS;
  for (int i = blockIdx.x*256 + threadIdx.x; i < rowN; i += gridDim.x*256){
    base[i] = 0;
    base[(long)129*rowN + i] = 0;
  }
  int colN = 128*CS;
  for (int i = blockIdx.x*256 + threadIdx.x; i < colN; i += gridDim.x*256){
    int row = 1 + i/CS, ch = i - (i/CS)*CS;
    base[((long)row*514 + 0)*CS + ch] = 0;
    base[((long)row*514 + 513)*CS + ch] = 0;
  }
}

// ---------------- fp32 -> bf16 weight conversion (flat) ----------------
__global__ __launch_bounds__(256) void cvt_f2b(const float* __restrict__ src, u16* __restrict__ dst){
  int i = (blockIdx.x*256 + threadIdx.x)*4;
  float4 v = *(const float4*)(src + i);
  ushort4 o;
  o.x=f2b(v.x); o.y=f2b(v.y); o.z=f2b(v.z); o.w=f2b(v.w);
  *(ushort4*)(dst + i) = o;
}

// ---------------- conv weight reorg, FRAGMENT ORDER: wr[dt][KP/32][q:4][h:2][r:16][8] ----------------
__global__ __launch_bounds__(256)
void prep_wr(const float* __restrict__ w, u16* __restrict__ wr,
             int CIN, int cs, int cof, int KP){
  int i = blockIdx.x*256 + threadIdx.x;
  int tot = 96*KP;
  if (i >= tot) return;
  int e  = i & 7;
  int r  = (i >> 3) & 15;
  int h  = (i >> 7) & 1;
  int q  = (i >> 8) & 3;
  int rest = i >> 10;
  int NK = KP >> 5;
  int ks = rest % NK, dt = rest / NK;
  int o = h*16 + r;
  int k = ks*32 + q*8 + e;
  float v = 0.f;
  int g = cof + k, df = g/cs, ch = g - df*cs;
  if (o < 24 && df < 3 && ch >= cof && ch < cof+CIN)
    v = w[((o*CIN + (ch-cof))*3 + dt)*3 + df];
  wr[i] = f2b(v);
}

// ---------------- copy x (CHW fp32) -> b72p NHWC ch48..72 AND xc24 NHWC compact ----------------
__global__ __launch_bounds__(256)
void copy_x2(const float* __restrict__ x, u16* __restrict__ b72p, u16* __restrict__ xc24){
  __shared__ u16 sh[24][520];
  int t = blockIdx.x & 127, b = blockIdx.x >> 7;
  const float* src = x + ((long)(b*24)*128 + t)*512;
  for (int c=0; c<24; c++){
    float2 v = *(const float2*)(src + (long)c*65536 + threadIdx.x*2);
    sh[c][threadIdx.x*2]   = f2b(v.x);
    sh[c][threadIdx.x*2+1] = f2b(v.y);
  }
  __syncthreads();
  long r72 = ((long)(b*130 + t+1))*514*72;
  long r24 = ((long)(b*130 + t+1))*514*24;
  for (int i = threadIdx.x; i < 1536; i += 256){
    int f = i/3, c0 = (i%3)*8;
    union {int4 q; u16 u[8];} o;
    #pragma unroll
    for (int j=0;j<8;j++) o.u[j] = sh[c0+j][f];
    *(int4*)(b72p + r72 + (long)(f+1)*72 + 48 + c0) = o.q;
    *(int4*)(xc24 + r24 + (long)(f+1)*24 + c0) = o.q;
  }
}

// ---------------- MFMA implicit-GEMM 3x3 conv v6 (known-good from 237us config) ----------------
template<int KP, int CS>
__global__ __launch_bounds__(256)
void conv_mfma(const u16* __restrict__ X, int coff, const u16* __restrict__ WR,
               const float* __restrict__ bias, u16* __restrict__ Y,
               float* __restrict__ raw){
  constexpr int NK = KP/32;
  __shared__ u16 WS[3*32*KP];
  __shared__ float ssum[4][32], ssq[4][32];
  __shared__ float g24s[24], g24q[24];
  __shared__ __align__(16) u16 Ysh[128*24];
  int bid = (blockIdx.x & 7)*64 + (blockIdx.x >> 3);   // grid 512, chunk 64
  int b = bid >> 7, t = bid & 127;
  int tid = threadIdx.x, wid = tid >> 6, l = tid & 63;
  int r = l & 15, q = l >> 4;

  for (int i = tid*8; i < 3*32*KP; i += 2048)
    *(int4*)(WS + i) = *(const int4*)(WR + i);

  float bv0 = bias[r];
  float bv1 = (r < 8) ? bias[16+r] : 0.f;
  float s0=0,q0=0,s1=0,q1=0;
  __syncthreads();

  #pragma unroll
  for (int fi=0; fi<4; fi++){
    int f0w = fi*128 + wid*32;
    f32x4 acc[2][2] = {};
    #pragma unroll
    for (int dt=0; dt<3; dt++){
      const u16* Ab = X + ((long)((b*130 + t+dt)*514 + f0w + r))*CS + coff + q*8;
      bf16x8 a[2][NK];
      #pragma unroll
      for (int ks=0; ks<NK; ks++){
        a[0][ks] = *(const bf16x8*)(Ab + ks*32);
        a[1][ks] = *(const bf16x8*)(Ab + (long)16*CS + ks*32);
      }
      #pragma unroll
      for (int ks=0; ks<NK; ks++){
        const u16* Bb = WS + ((dt*NK + ks)*4 + q)*256 + r*8;
        bf16x8 b0 = *(const bf16x8*)(Bb);
        bf16x8 b1 = *(const bf16x8*)(Bb + 128);
        acc[0][0] = __builtin_amdgcn_mfma_f32_16x16x32_bf16(a[0][ks],b0,acc[0][0],0,0,0);
        acc[0][1] = __builtin_amdgcn_mfma_f32_16x16x32_bf16(a[0][ks],b1,acc[0][1],0,0,0);
        acc[1][0] = __builtin_amdgcn_mfma_f32_16x16x32_bf16(a[1][ks],b0,acc[1][0],0,0,0);
        acc[1][1] = __builtin_amdgcn_mfma_f32_16x16x32_bf16(a[1][ks],b1,acc[1][1],0,0,0);
      }
    }
    #pragma unroll
    for (int m=0;m<2;m++){
      #pragma unroll
      for (int j=0;j<4;j++){
        acc[m][0][j] += bv0; acc[m][1][j] += bv1;
        s0 += acc[m][0][j]; q0 += acc[m][0][j]*acc[m][0][j];
        s1 += acc[m][1][j]; q1 += acc[m][1][j]*acc[m][1][j];
      }
    }
    __syncthreads();
    #pragma unroll
    for (int m=0;m<2;m++){
      int fr = wid*32 + m*16 + q*4;
      #pragma unroll
      for (int j=0;j<4;j++){
        Ysh[(fr+j)*24 + r] = f2b(acc[m][0][j]);
        if (r < 8) Ysh[(fr+j)*24 + 16 + r] = f2b(acc[m][1][j]);
      }
    }
    __syncthreads();
    long Yb = ((long)((b*128 + t)*512) + fi*128)*24;
    const int4* sp = (const int4*)Ysh;
    for (int i = tid; i < 384; i += 256)
      *(int4*)(Y + Yb + (long)i*8) = sp[i];
  }

  #pragma unroll
  for (int off=16; off<=32; off<<=1){
    s0 += __shfl_xor(s0, off, 64); q0 += __shfl_xor(q0, off, 64);
    s1 += __shfl_xor(s1, off, 64); q1 += __shfl_xor(q1, off, 64);
  }
  if (q == 0){
    ssum[wid][r] = s0;     ssq[wid][r] = q0;
    ssum[wid][16+r] = s1;  ssq[wid][16+r] = q1;
  }
  __syncthreads();
  if (tid < 24){
    g24s[tid] = ssum[0][tid]+ssum[1][tid]+ssum[2][tid]+ssum[3][tid];
    g24q[tid] = ssq[0][tid]+ssq[1][tid]+ssq[2][tid]+ssq[3][tid];
  }
  __syncthreads();
  if (tid < 4){
    float as=0, aq=0;
    #pragma unroll
    for (int j=0;j<6;j++){ as += g24s[tid*6+j]; aq += g24q[tid*6+j]; }
    atomicAdd(&raw[b*4+tid], as);
    atomicAdd(&raw[16+b*4+tid], aq);
  }
}

// ---------------- finalize: raw stats -> per-(b,c) scale/offset tables ----------------
__global__ void finalize_scoff(const float* __restrict__ raw, const float* __restrict__ gw,
                               const float* __restrict__ gb, float invN,
                               float* __restrict__ scA, float* __restrict__ scB){
  int i = threadIdx.x;
  if (i < 96){
    int b = i/24, c = i%24, g = b*4 + c/6;
    float m = raw[g]*invN;
    float var = raw[16+g]*invN - m*m;
    float is = rsqrtf(var + EPS);
    float sc = is*gw[c];
    scA[i] = sc;
    scB[i] = gb[c] - m*sc;
  }
}

// ---------------- normalize+relu: Y NHWC -> b72p channel slice ----------------
__global__ __launch_bounds__(256)
void norm_relu_nhwc(const u16* __restrict__ Y, u16* __restrict__ dst, int coff,
                    const float* __restrict__ scA, const float* __restrict__ scB){
  long e = ((long)blockIdx.x*256 + threadIdx.x)*8;
  int c0 = (int)(e % 24);
  long fi = e / 24;
  int f = (int)(fi & 511);
  int bt = (int)(fi >> 9); int t = bt & 127, b = bt >> 7;
  float4 sa0 = *(const float4*)(scA + b*24 + c0);
  float4 sa1 = *(const float4*)(scA + b*24 + c0 + 4);
  float4 sb0 = *(const float4*)(scB + b*24 + c0);
  float4 sb1 = *(const float4*)(scB + b*24 + c0 + 4);
  float A[8]  = {sa0.x,sa0.y,sa0.z,sa0.w,sa1.x,sa1.y,sa1.z,sa1.w};
  float Bv[8] = {sb0.x,sb0.y,sb0.z,sb0.w,sb1.x,sb1.y,sb1.z,sb1.w};
  union {int4 q; u16 u[8];} pk; pk.q = *(const int4*)(Y + e);
  union {int4 q; u16 u[8];} o;
  #pragma unroll
  for (int j=0;j<8;j++){ float v = b2f(pk.u[j])*A[j] + Bv[j]; o.u[j] = f2b(v>0.f?v:0.f); }
  *(int4*)(dst + ((long)(b*130 + t+1)*514 + (f+1))*72 + coff + c0) = o.q;
}

// ---------------- normalize+relu + NHWC->CHW transpose (conv2 output -> xr) ----------------
__global__ __launch_bounds__(256)
void norm_relu_chw(const u16* __restrict__ Y, u16* __restrict__ xr,
                   const float* __restrict__ scA, const float* __restrict__ scB){
  __shared__ u16 sh[24][520];
  __shared__ float sA[24], sB[24];
  int t = blockIdx.x & 127, b = blockIdx.x >> 7;
  if (threadIdx.x < 24){ sA[threadIdx.x] = scA[b*24+threadIdx.x]; sB[threadIdx.x] = scB[b*24+threadIdx.x]; }
  __syncthreads();
  const u16* src = Y + ((long)(b*128+t))*12288;
  for (int i = threadIdx.x; i < 1536; i += 256){
    int e = i*8; int c0 = e % 24; int f = e / 24;
    union {int4 q; u16 u[8];} pk; pk.q = *(const int4*)(src + e);
    #pragma unroll
    for (int j=0;j<8;j++){
      float v = b2f(pk.u[j])*sA[c0+j] + sB[c0+j];
      sh[c0+j][f] = f2b(v>0.f?v:0.f);
    }
  }
  __syncthreads();
  for (int i = threadIdx.x; i < 1536; i += 256){
    int c = i >> 6, fq = (i & 63)*8;
    union {int4 q; u16 u[8];} o;
    #pragma unroll
    for (int j=0;j<8;j++) o.u[j] = sh[c][fq+j];
    *(int4*)(xr + ((long)((b*24+c)*128 + t))*512 + fq) = o.q;
  }
}

// ---------------- elementwise normalize+relu on CHW rows (h1, rowlen 192) ----------------
__global__ __launch_bounds__(256)
void norm_chw(u16* __restrict__ h, const float* __restrict__ scA, const float* __restrict__ scB){
  long e = ((long)blockIdx.x*256 + threadIdx.x)*8;
  long row = e / 192;
  int c = (int)((row >> 7) % 24);
  int b = (int)(row / 3072);
  float sc = scA[b*24+c], off = scB[b*24+c];
  union {int4 q; u16 u[8];} pk; pk.q = *(const int4*)(h + e);
  #pragma unroll
  for (int j=0;j<8;j++){ float v = b2f(pk.u[j])*sc + off; pk.u[j] = f2b(v>0.f?v:0.f); }
  *(int4*)(h + e) = pk.q;
}

// ---------------- LDS-staged MFMA GEMM, depth-2 counted-vmcnt pipeline (3 buffers) ----------------
// Tile 128 x (NF*32). 4 waves 2x2 (each wave 64 x NF*16). Padded LDS repack on store.
template<int NF, bool STORE>
__global__ __launch_bounds__(256)
void gemm_lds(const u16* __restrict__ A, const u16* __restrict__ Bt, u16* __restrict__ C,
              int N, int K, int NBX, float* __restrict__ raw){
  constexpr int BN = NF*32;
  constexpr int BNP = BN + 4;          // pad: q-groups land on disjoint bank octets
  constexpr int ABUF = 128*32;
  constexpr int BBUF = BN*32;
  __shared__ __align__(16) u16 SH[3*(ABUF+BBUF)];
  u16* Asb = SH;
  u16* Bsb = SH + 3*ABUF;
  int tid = threadIdx.x, wid = tid >> 6, l = tid & 63;
  int r = l & 15, q = l >> 4;
  int wr = wid >> 1, wc = wid & 1;
  int chunk = gridDim.x >> 3;
  int lin = (blockIdx.x & 7)*chunk + (blockIdx.x >> 3);
  int bx = lin % NBX, by = lin / NBX;
  long m0 = (long)by*128;
  int n0 = bx*BN;

  int arow[2], ach[2], aslot[2];
  #pragma unroll
  for (int j=0;j<2;j++){
    int idx = (wid*2+j)*64 + l;
    aslot[j] = idx*8;
    arow[j]  = ((idx>>6)<<4) | (idx & 15);
    ach[j]   = ((idx>>4) & 3)*8;
  }
  int brow[NF/2], bch[NF/2], bslot[NF/2];
  #pragma unroll
  for (int j=0;j<NF/2;j++){
    int idx = (wid*(NF/2)+j)*64 + l;
    bslot[j] = idx*8;
    brow[j]  = ((idx>>6)<<4) | (idx & 15);
    bch[j]   = ((idx>>4) & 3)*8;
  }

  f32x4 acc[4][NF];
  #pragma unroll
  for (int mf=0;mf<4;mf++)
    #pragma unroll
    for (int nf=0;nf<NF;nf++) acc[mf][nf] = (f32x4){0.f,0.f,0.f,0.f};

  int nt = K >> 5;
  #pragma unroll
  for (int j=0;j<2;j++)    gload16(A  + (m0+arow[j])*K + ach[j], Asb + aslot[j]);
  #pragma unroll
  for (int j=0;j<NF/2;j++) gload16(Bt + (long)(n0+brow[j])*K + bch[j], Bsb + bslot[j]);
  #pragma unroll
  for (int j=0;j<2;j++)    gload16(A  + (m0+arow[j])*K + 32 + ach[j], Asb + ABUF + aslot[j]);
  #pragma unroll
  for (int j=0;j<NF/2;j++) gload16(Bt + (long)(n0+brow[j])*K + 32 + bch[j], Bsb + BBUF + bslot[j]);

  int c0 = 0;
  for (int kt=0; kt<nt; kt++){
    if constexpr (NF==8)      asm volatile("s_waitcnt vmcnt(6)" ::: "memory");
    else if constexpr (NF==4) asm volatile("s_waitcnt vmcnt(4)" ::: "memory");
    else                      asm volatile("s_waitcnt vmcnt(3)" ::: "memory");
    __builtin_amdgcn_s_barrier();
    __builtin_amdgcn_sched_barrier(0);
    if (kt+2 < nt){
      int c2 = c0+2; if (c2>=3) c2-=3;
      int ko = (kt+2)*32;
      #pragma unroll
      for (int j=0;j<2;j++)    gload16(A  + (m0+arow[j])*K + ko + ach[j], Asb + c2*ABUF + aslot[j]);
      #pragma unroll
      for (int j=0;j<NF/2;j++) gload16(Bt + (long)(n0+brow[j])*K + ko + bch[j], Bsb + c2*BBUF + bslot[j]);
    }
    const u16* Ac = Asb + c0*ABUF;
    const u16* Bc = Bsb + c0*BBUF;
    bf16x8 af[4], bfv[NF];
    #pragma unroll
    for (int mf=0;mf<4;mf++) af[mf]  = *(const bf16x8*)(Ac + (((wr*4+mf)*4 + q)*16 + r)*8);
    #pragma unroll
    for (int nf=0;nf<NF;nf++) bfv[nf] = *(const bf16x8*)(Bc + (((wc*NF+nf)*4 + q)*16 + r)*8);
    #pragma unroll
    for (int mf=0;mf<4;mf++)
      #pragma unroll
      for (int nf=0;nf<NF;nf++)
        acc[mf][nf] = __builtin_amdgcn_mfma_f32_16x16x32_bf16(af[mf], bfv[nf], acc[mf][nf], 0,0,0);
    c0 = (c0+1==3) ? 0 : c0+1;
  }

  float s=0.f, ss=0.f;
  #pragma unroll
  for (int mf=0;mf<4;mf++)
    #pragma unroll
    for (int nf=0;nf<NF;nf++)
      #pragma unroll
      for (int j=0;j<4;j++){ float v = acc[mf][nf][j]; s += v; ss += v*v; }
  #pragma unroll
  for (int off=32; off>0; off>>=1){ s += __shfl_down(s,off,64); ss += __shfl_down(ss,off,64); }
  __shared__ float rs[4], rss[4];
  if (l==0){ rs[wid]=s; rss[wid]=ss; }
  __syncthreads();                 // all compute done -> SH reusable
  if (tid==0){
    int bc = (int)(m0 >> 7);
    int g = (bc/24)*4 + (bc%24)/6;
    atomicAdd(&raw[g],    rs[0]+rs[1]+rs[2]+rs[3]);
    atomicAdd(&raw[16+g], rss[0]+rss[1]+rss[2]+rss[3]);
  }

  if constexpr (STORE){
    #pragma unroll
    for (int mf=0;mf<4;mf++){
      int row = wr*64 + mf*16 + q*4;
      #pragma unroll
      for (int nf=0;nf<NF;nf++){
        int col = wc*(NF*16) + nf*16 + r;
        #pragma unroll
        for (int j=0;j<4;j++)
          SH[(row+j)*BNP + col] = f2b(acc[mf][nf][j]);
      }
    }
    __syncthreads();
    constexpr int RPT = BN/16;
    #pragma unroll
    for (int k=0;k<RPT;k++){
      int j = tid + k*256;
      int row = j / (BN/8), col8 = (j % (BN/8))*8;
      *(int4*)(C + (m0+row)*N + n0 + col8) = *(const int4*)(SH + row*BNP + col8);
    }
  }
}

// ---------------- attention: att[4][6] (fp32) ----------------
__global__ void attention_kernel(const float* __restrict__ c, const float* __restrict__ wq,
                                 const float* __restrict__ bq, const float* __restrict__ keys,
                                 float* __restrict__ att){
  __shared__ float q[4][32];
  __shared__ float s[4][6];
  int t = threadIdx.x;
  if (t < 128){
    int b = t >> 5, k = t & 31;
    float a = bq[k];
    for (int j=0;j<32;j++) a += c[b*32+j] * wq[k*32+j];
    q[b][k] = a;
  }
  __syncthreads();
  if (t < 24){
    int b = t/6, n = t%6;
    float a = 0.f;
    for (int k=0;k<32;k++) a += q[b][k]*keys[k*6+n];
    s[b][n] = a * 0.17677669529663689f;
  }
  __syncthreads();
  if (t < 4){
    float mx = -1e30f;
    for (int n=0;n<6;n++) mx = fmaxf(mx, s[t][n]);
    float e[6], sm=0.f;
    for (int n=0;n<6;n++){ e[n]=expf(s[t][n]-mx); sm+=e[n]; }
    for (int n=0;n<6;n++) att[t*6+n] = e[n]/sm;
  }
}

// ---------------- final: out(fp32) = x_ + sum_n relu(gn2(h2))[...,n]*att[b,n] ----------------
__global__ __launch_bounds__(256)
void final_mix(const u16* __restrict__ h2, const u16* __restrict__ xr,
               const float* __restrict__ scA, const float* __restrict__ scB,
               const float* __restrict__ att, float* __restrict__ out){
  int gid = blockIdx.x*256 + threadIdx.x;
  int fq = gid & 127;
  int t  = (gid >> 7) & 127;
  int bc = gid >> 14;
  int c  = bc % 24, b = bc / 24;
  float sc = scA[b*24+c];
  float off = scB[b*24+c];
  float a[6];
  #pragma unroll
  for (int n=0;n<6;n++) a[n] = att[b*6+n];

  long hbase = (((long)bc*Tn + t))*3072 + (long)fq*24;
  union { int4 v[3]; u16 u[24]; } hv;
  const int4* hp = (const int4*)(h2 + hbase);
  hv.v[0]=hp[0]; hv.v[1]=hp[1]; hv.v[2]=hp[2];

  long xbase = (((long)bc*Tn + t))*Fn + (long)fq*4;
  union { unsigned long long q; u16 u[4]; } xv;
  xv.q = *(const unsigned long long*)(xr + xbase);

  float4 ov;
  float* op = &ov.x;
  #pragma unroll
  for (int j=0;j<4;j++){
    float accv = b2f(xv.u[j]);
    #pragma unroll
    for (int n=0;n<6;n++){
      float hvf = b2f(hv.u[j*6+n])*sc + off;
      hvf = hvf > 0.f ? hvf : 0.f;
      accv += hvf * a[n];
    }
    op[j] = accv;
  }
  *(float4*)(out + xbase) = ov;
}

extern "C" void kernel_launch(void* const* d_in, const int* in_sizes, int n_in,
                              void* d_out, int out_size, void* d_ws, size_t ws_size,
                              hipStream_t stream){
  const float* x   = (const float*)d_in[0];
  const float* c   = (const float*)d_in[1];
  const float* cw0 = (const float*)d_in[2];  const float* cb0 = (const float*)d_in[3];
  const float* gw0 = (const float*)d_in[4];  const float* gb0 = (const float*)d_in[5];
  const float* cw1 = (const float*)d_in[6];  const float* cb1 = (const float*)d_in[7];
  const float* gw1 = (const float*)d_in[8];  const float* gb1 = (const float*)d_in[9];
  const float* cw2 = (const float*)d_in[10]; const float* cb2 = (const float*)d_in[11];
  const float* gw2 = (const float*)d_in[12]; const float* gb2 = (const float*)d_in[13];
  const float* tw1 = (const float*)d_in[14]; const float* tg1w= (const float*)d_in[15]; const float* tg1b=(const float*)d_in[16];
  const float* tw2 = (const float*)d_in[17]; const float* tg2w= (const float*)d_in[18]; const float* tg2b=(const float*)d_in[19];
  const float* wqp = (const float*)d_in[20]; const float* bqp = (const float*)d_in[21]; const float* keys=(const float*)d_in[22];

  char* ws = (char*)d_ws;
  u16*   xr     = (u16*)(ws + 0);               // 12,582,912 B  [12288,512] bf16 CHW
  u16*   h1     = (u16*)(ws + 12582912);        //  4,718,592 B  [12288,192]
  u16*   tw1b   = (u16*)(ws + 17301504);        //    196,608 B
  u16*   tw2b   = (u16*)(ws + 17498112);        //  1,179,648 B
  float* stats5 = (float*)(ws + 18677760);      //        128 B
  float* scoff5 = (float*)(ws + 18677888);      //        768 B
  float* att    = (float*)(ws + 18678656);      //        128 B
  // ---- h2 span (reused during conv phase) ----
  u16*   h2     = (u16*)(ws + 18680832);        // 75,497,472 B  [12288,3072]
  u16*   Y      = (u16*)(ws + 18680832);        // 12,582,912 B  NHWC conv out [4,128,512,24]
  u16*   b72p   = (u16*)(ws + 31263744);        // 38,488,320 B  NHWC padded [4,130,514,72]
  u16*   xc24   = (u16*)(ws + 69752064);        // 12,829,440 B (+256 slack) NHWC padded [4,130,514,24]
  float* stats14= (float*)(ws + 82581760);      //        512 B
  float* scoff14= (float*)(ws + 82582272);      //      3,072 B
  u16*   wr0    = (u16*)(ws + 82585344);        //     18,432 B
  u16*   wr1    = (u16*)(ws + 82603776);        //     36,864 B
  u16*   wr2    = (u16*)(ws + 82640640);        //     43,008 B

  border_zero<<<dim3(32,4),256,0,stream>>>(b72p, 72);
  border_zero<<<dim3(16,4),256,0,stream>>>(xc24, 24);
  zero_stats2<<<1,256,0,stream>>>(stats14, stats5);

  prep_wr<<<36,256,0,stream>>>(cw0, wr0, 24, 24, 0, 96);
  prep_wr<<<72,256,0,stream>>>(cw1, wr1, 48, 72, 24, 192);
  prep_wr<<<84,256,0,stream>>>(cw2, wr2, 72, 72, 0, 224);
  cvt_f2b<<<96,256,0,stream>>>(tw1, tw1b);
  cvt_f2b<<<576,256,0,stream>>>(tw2, tw2b);
  copy_x2<<<512,256,0,stream>>>(x, b72p, xc24);
  attention_kernel<<<1,128,0,stream>>>(c, wqp, bqp, keys, att);

  // ---- conv block 0 ----
  conv_mfma<96,24><<<512,256,0,stream>>>(xc24, 0, wr0, cb0, Y, stats14+0);
  finalize_scoff<<<1,96,0,stream>>>(stats14+0, gw0, gb0, 1.f/393216.f, scoff14+0, scoff14+96);
  norm_relu_nhwc<<<3072,256,0,stream>>>(Y, b72p, 24, scoff14+0, scoff14+96);

  // ---- conv block 1 ----
  conv_mfma<192,72><<<512,256,0,stream>>>(b72p, 24, wr1, cb1, Y, stats14+32);
  finalize_scoff<<<1,96,0,stream>>>(stats14+32, gw1, gb1, 1.f/393216.f, scoff14+192, scoff14+288);
  norm_relu_nhwc<<<3072,256,0,stream>>>(Y, b72p, 0, scoff14+192, scoff14+288);

  // ---- conv block 2 -> xr (CHW) ----
  conv_mfma<224,72><<<512,256,0,stream>>>(b72p, 0, wr2, cb2, Y, stats14+64);
  finalize_scoff<<<1,96,0,stream>>>(stats14+64, gw2, gb2, 1.f/393216.f, scoff14+384, scoff14+480);
  norm_relu_chw<<<512,256,0,stream>>>(Y, xr, scoff14+384, scoff14+480);

  // ---- TDF: gemm1 (12288x192x512) + GN + relu ----
  gemm_lds<2,true><<<288,256,0,stream>>>(xr, tw1b, h1, 192, 512, 3, stats14+96);
  finalize_scoff<<<1,96,0,stream>>>(stats14+96, tg1w, tg1b, 1.f/147456.f, scoff14+576, scoff14+672);
  norm_chw<<<1152,256,0,stream>>>(h1, scoff14+576, scoff14+672);

  // ---- TDF: gemm2 (12288x3072x192), tile 128x256 ----
  gemm_lds<8,true><<<1152,256,0,stream>>>(h1, tw2b, h2, 3072, 192, 12, stats5);
  finalize_scoff<<<1,96,0,stream>>>(stats5, tg2w, tg2b, 1.f/2359296.f, scoff5, scoff5+96);

  // ---- final mix ----
  final_mix<<<6144,256,0,stream>>>(h2, xr, scoff5, scoff5+96, att, (float*)d_out);
}

// Round 13
// 230.679 us; speedup vs baseline: 1.1934x; 1.0629x over previous
//
#include <hip/hip_runtime.h>
#include <hip/hip_bf16.h>

typedef unsigned short u16;
typedef unsigned int u32;

#define Tn 128
#define Fn 512
#define HWc (Tn*Fn)
#define EPS 1e-5f

using bf16x8 = __attribute__((ext_vector_type(8))) short;
using f32x4  = __attribute__((ext_vector_type(4))) float;

__device__ __forceinline__ float b2f(u16 x){ return __uint_as_float(((u32)x)<<16); }
__device__ __forceinline__ u16 f2b(float f){
  __hip_bfloat16 h = __float2bfloat16(f);
  return *reinterpret_cast<u16*>(&h);
}

// async global->LDS, 16B per lane
__device__ __forceinline__ void gload16(const u16* g, u16* l){
  __builtin_amdgcn_global_load_lds((const __attribute__((address_space(1))) void*)g,
                                   (__attribute__((address_space(3))) void*)l, 16, 0, 0);
}

// ---------------- zero stats ----------------
__global__ void zero_stats2(float* a, float* b){
  int i = threadIdx.x;
  if (i < 128) a[i] = 0.f;
  else if (i < 160) b[i-128] = 0.f;
}

// ---------------- zero only the padded borders of an NHWC-padded buffer ----------------
__global__ __launch_bounds__(256) void border_zero(u16* __restrict__ p, int CS){
  int b = blockIdx.y;
  u16* base = p + (long)b*130*514*CS;
  int rowN = 514*CS;
  for (int i = blockIdx.x*256 + threadIdx.x; i < rowN; i += gridDim.x*256){
    base[i] = 0;
    base[(long)129*rowN + i] = 0;
  }
  int colN = 128*CS;
  for (int i = blockIdx.x*256 + threadIdx.x; i < colN; i += gridDim.x*256){
    int row = 1 + i/CS, ch = i - (i/CS)*CS;
    base[((long)row*514 + 0)*CS + ch] = 0;
    base[((long)row*514 + 513)*CS + ch] = 0;
  }
}

// ---------------- fp32 -> bf16 weight conversion (flat) ----------------
__global__ __launch_bounds__(256) void cvt_f2b(const float* __restrict__ src, u16* __restrict__ dst){
  int i = (blockIdx.x*256 + threadIdx.x)*4;
  float4 v = *(const float4*)(src + i);
  ushort4 o;
  o.x=f2b(v.x); o.y=f2b(v.y); o.z=f2b(v.z); o.w=f2b(v.w);
  *(ushort4*)(dst + i) = o;
}

// ---------------- conv weight reorg, FRAGMENT ORDER: wr[dt][KP/32][q:4][h:2][r:16][8] ----------------
__global__ __launch_bounds__(256)
void prep_wr(const float* __restrict__ w, u16* __restrict__ wr,
             int CIN, int cs, int cof, int KP){
  int i = blockIdx.x*256 + threadIdx.x;
  int tot = 96*KP;
  if (i >= tot) return;
  int e  = i & 7;
  int r  = (i >> 3) & 15;
  int h  = (i >> 7) & 1;
  int q  = (i >> 8) & 3;
  int rest = i >> 10;
  int NK = KP >> 5;
  int ks = rest % NK, dt = rest / NK;
  int o = h*16 + r;
  int k = ks*32 + q*8 + e;
  float v = 0.f;
  int g = cof + k, df = g/cs, ch = g - df*cs;
  if (o < 24 && df < 3 && ch >= cof && ch < cof+CIN)
    v = w[((o*CIN + (ch-cof))*3 + dt)*3 + df];
  wr[i] = f2b(v);
}

// ---------------- copy x (CHW fp32) -> b72p NHWC ch48..72 AND xc24 NHWC compact ----------------
__global__ __launch_bounds__(256)
void copy_x2(const float* __restrict__ x, u16* __restrict__ b72p, u16* __restrict__ xc24){
  __shared__ u16 sh[24][520];
  int t = blockIdx.x & 127, b = blockIdx.x >> 7;
  const float* src = x + ((long)(b*24)*128 + t)*512;
  for (int c=0; c<24; c++){
    float2 v = *(const float2*)(src + (long)c*65536 + threadIdx.x*2);
    sh[c][threadIdx.x*2]   = f2b(v.x);
    sh[c][threadIdx.x*2+1] = f2b(v.y);
  }
  __syncthreads();
  long r72 = ((long)(b*130 + t+1))*514*72;
  long r24 = ((long)(b*130 + t+1))*514*24;
  for (int i = threadIdx.x; i < 1536; i += 256){
    int f = i/3, c0 = (i%3)*8;
    union {int4 q; u16 u[8];} o;
    #pragma unroll
    for (int j=0;j<8;j++) o.u[j] = sh[c0+j][f];
    *(int4*)(b72p + r72 + (long)(f+1)*72 + 48 + c0) = o.q;
    *(int4*)(xc24 + r24 + (long)(f+1)*24 + c0) = o.q;
  }
}

// ---------------- MFMA implicit-GEMM 3x3 conv v6 ----------------
template<int KP, int CS>
__global__ __launch_bounds__(256)
void conv_mfma(const u16* __restrict__ X, int coff, const u16* __restrict__ WR,
               const float* __restrict__ bias, u16* __restrict__ Y,
               float* __restrict__ raw){
  constexpr int NK = KP/32;
  __shared__ u16 WS[3*32*KP];
  __shared__ float ssum[4][32], ssq[4][32];
  __shared__ float g24s[24], g24q[24];
  __shared__ __align__(16) u16 Ysh[128*24];
  int bid = (blockIdx.x & 7)*64 + (blockIdx.x >> 3);   // grid 512, chunk 64
  int b = bid >> 7, t = bid & 127;
  int tid = threadIdx.x, wid = tid >> 6, l = tid & 63;
  int r = l & 15, q = l >> 4;

  for (int i = tid*8; i < 3*32*KP; i += 2048)
    *(int4*)(WS + i) = *(const int4*)(WR + i);

  float bv0 = bias[r];
  float bv1 = (r < 8) ? bias[16+r] : 0.f;
  float s0=0,q0=0,s1=0,q1=0;
  __syncthreads();

  #pragma unroll
  for (int fi=0; fi<4; fi++){
    int f0w = fi*128 + wid*32;
    f32x4 acc[2][2] = {};
    #pragma unroll
    for (int dt=0; dt<3; dt++){
      const u16* Ab = X + ((long)((b*130 + t+dt)*514 + f0w + r))*CS + coff + q*8;
      bf16x8 a[2][NK];
      #pragma unroll
      for (int ks=0; ks<NK; ks++){
        a[0][ks] = *(const bf16x8*)(Ab + ks*32);
        a[1][ks] = *(const bf16x8*)(Ab + (long)16*CS + ks*32);
      }
      #pragma unroll
      for (int ks=0; ks<NK; ks++){
        const u16* Bb = WS + ((dt*NK + ks)*4 + q)*256 + r*8;
        bf16x8 b0 = *(const bf16x8*)(Bb);
        bf16x8 b1 = *(const bf16x8*)(Bb + 128);
        acc[0][0] = __builtin_amdgcn_mfma_f32_16x16x32_bf16(a[0][ks],b0,acc[0][0],0,0,0);
        acc[0][1] = __builtin_amdgcn_mfma_f32_16x16x32_bf16(a[0][ks],b1,acc[0][1],0,0,0);
        acc[1][0] = __builtin_amdgcn_mfma_f32_16x16x32_bf16(a[1][ks],b0,acc[1][0],0,0,0);
        acc[1][1] = __builtin_amdgcn_mfma_f32_16x16x32_bf16(a[1][ks],b1,acc[1][1],0,0,0);
      }
    }
    #pragma unroll
    for (int m=0;m<2;m++){
      #pragma unroll
      for (int j=0;j<4;j++){
        acc[m][0][j] += bv0; acc[m][1][j] += bv1;
        s0 += acc[m][0][j]; q0 += acc[m][0][j]*acc[m][0][j];
        s1 += acc[m][1][j]; q1 += acc[m][1][j]*acc[m][1][j];
      }
    }
    __syncthreads();
    #pragma unroll
    for (int m=0;m<2;m++){
      int fr = wid*32 + m*16 + q*4;
      #pragma unroll
      for (int j=0;j<4;j++){
        Ysh[(fr+j)*24 + r] = f2b(acc[m][0][j]);
        if (r < 8) Ysh[(fr+j)*24 + 16 + r] = f2b(acc[m][1][j]);
      }
    }
    __syncthreads();
    long Yb = ((long)((b*128 + t)*512) + fi*128)*24;
    const int4* sp = (const int4*)Ysh;
    for (int i = tid; i < 384; i += 256)
      *(int4*)(Y + Yb + (long)i*8) = sp[i];
  }

  #pragma unroll
  for (int off=16; off<=32; off<<=1){
    s0 += __shfl_xor(s0, off, 64); q0 += __shfl_xor(q0, off, 64);
    s1 += __shfl_xor(s1, off, 64); q1 += __shfl_xor(q1, off, 64);
  }
  if (q == 0){
    ssum[wid][r] = s0;     ssq[wid][r] = q0;
    ssum[wid][16+r] = s1;  ssq[wid][16+r] = q1;
  }
  __syncthreads();
  if (tid < 24){
    g24s[tid] = ssum[0][tid]+ssum[1][tid]+ssum[2][tid]+ssum[3][tid];
    g24q[tid] = ssq[0][tid]+ssq[1][tid]+ssq[2][tid]+ssq[3][tid];
  }
  __syncthreads();
  if (tid < 4){
    float as=0, aq=0;
    #pragma unroll
    for (int j=0;j<6;j++){ as += g24s[tid*6+j]; aq += g24q[tid*6+j]; }
    atomicAdd(&raw[b*4+tid], as);
    atomicAdd(&raw[16+b*4+tid], aq);
  }
}

// ---------------- normalize+relu: Y NHWC -> b72p channel slice (inline GN params) ----------------
__global__ __launch_bounds__(256)
void norm_relu_nhwc(const u16* __restrict__ Y, u16* __restrict__ dst, int coff,
                    const float* __restrict__ raw, const float* __restrict__ gw,
                    const float* __restrict__ gb, float invN){
  __shared__ float sA[24], sB[24];
  int bb = blockIdx.x / 768;                 // block spans a single batch b
  if (threadIdx.x < 24){
    int g = bb*4 + threadIdx.x/6;
    float m = raw[g]*invN;
    float var = raw[16+g]*invN - m*m;
    float is = rsqrtf(var + EPS);
    float sc = is*gw[threadIdx.x];
    sA[threadIdx.x] = sc;
    sB[threadIdx.x] = gb[threadIdx.x] - m*sc;
  }
  __syncthreads();
  long e = ((long)blockIdx.x*256 + threadIdx.x)*8;
  int c0 = (int)(e % 24);
  long fi = e / 24;
  int f = (int)(fi & 511);
  int bt = (int)(fi >> 9); int t = bt & 127, b = bt >> 7;
  union {int4 q; u16 u[8];} pk; pk.q = *(const int4*)(Y + e);
  union {int4 q; u16 u[8];} o;
  #pragma unroll
  for (int j=0;j<8;j++){
    float v = b2f(pk.u[j])*sA[c0+j] + sB[c0+j];
    o.u[j] = f2b(v>0.f?v:0.f);
  }
  *(int4*)(dst + ((long)(b*130 + t+1)*514 + (f+1))*72 + coff + c0) = o.q;
}

// ---------------- normalize+relu + NHWC->CHW transpose (inline GN params) ----------------
__global__ __launch_bounds__(256)
void norm_relu_chw(const u16* __restrict__ Y, u16* __restrict__ xr,
                   const float* __restrict__ raw, const float* __restrict__ gw,
                   const float* __restrict__ gb, float invN){
  __shared__ u16 sh[24][520];
  __shared__ float sA[24], sB[24];
  int t = blockIdx.x & 127, b = blockIdx.x >> 7;
  if (threadIdx.x < 24){
    int g = b*4 + threadIdx.x/6;
    float m = raw[g]*invN;
    float var = raw[16+g]*invN - m*m;
    float is = rsqrtf(var + EPS);
    float sc = is*gw[threadIdx.x];
    sA[threadIdx.x] = sc;
    sB[threadIdx.x] = gb[threadIdx.x] - m*sc;
  }
  __syncthreads();
  const u16* src = Y + ((long)(b*128+t))*12288;
  for (int i = threadIdx.x; i < 1536; i += 256){
    int e = i*8; int c0 = e % 24; int f = e / 24;
    union {int4 q; u16 u[8];} pk; pk.q = *(const int4*)(src + e);
    #pragma unroll
    for (int j=0;j<8;j++){
      float v = b2f(pk.u[j])*sA[c0+j] + sB[c0+j];
      sh[c0+j][f] = f2b(v>0.f?v:0.f);
    }
  }
  __syncthreads();
  for (int i = threadIdx.x; i < 1536; i += 256){
    int c = i >> 6, fq = (i & 63)*8;
    union {int4 q; u16 u[8];} o;
    #pragma unroll
    for (int j=0;j<8;j++) o.u[j] = sh[c][fq+j];
    *(int4*)(xr + ((long)((b*24+c)*128 + t))*512 + fq) = o.q;
  }
}

// ---------------- elementwise normalize+relu on CHW rows (h1), inline GN params ----------------
__global__ __launch_bounds__(256)
void norm_chw(u16* __restrict__ h, const float* __restrict__ raw,
              const float* __restrict__ gw, const float* __restrict__ gb, float invN){
  __shared__ float s_sc, s_off;
  int bc = blockIdx.x / 12;                 // block spans a single (b,c)
  if (threadIdx.x == 0){
    int b = bc/24, c = bc%24;
    int g = b*4 + c/6;
    float m = raw[g]*invN;
    float var = raw[16+g]*invN - m*m;
    float is = rsqrtf(var + EPS);
    float sc = is*gw[c];
    s_sc = sc;
    s_off = gb[c] - m*sc;
  }
  __syncthreads();
  float sc = s_sc, off = s_off;
  long e = ((long)blockIdx.x*256 + threadIdx.x)*8;
  union {int4 q; u16 u[8];} pk; pk.q = *(const int4*)(h + e);
  #pragma unroll
  for (int j=0;j<8;j++){ float v = b2f(pk.u[j])*sc + off; pk.u[j] = f2b(v>0.f?v:0.f); }
  *(int4*)(h + e) = pk.q;
}

// ---------------- LDS-staged MFMA GEMM, depth-2 counted-vmcnt pipeline (3 buffers) ----------------
template<int NF, bool STORE>
__global__ __launch_bounds__(256)
void gemm_lds(const u16* __restrict__ A, const u16* __restrict__ Bt, u16* __restrict__ C,
              int N, int K, int NBX, float* __restrict__ raw){
  constexpr int BN = NF*32;
  constexpr int BNP = BN + 4;          // pad: q-row groups -> disjoint bank octets
  constexpr int ABUF = 128*32;
  constexpr int BBUF = BN*32;
  __shared__ __align__(16) u16 SH[3*(ABUF+BBUF)];
  u16* Asb = SH;
  u16* Bsb = SH + 3*ABUF;
  int tid = threadIdx.x, wid = tid >> 6, l = tid & 63;
  int r = l & 15, q = l >> 4;
  int wr = wid >> 1, wc = wid & 1;
  int chunk = gridDim.x >> 3;
  int lin = (blockIdx.x & 7)*chunk + (blockIdx.x >> 3);
  int bx = lin % NBX, by = lin / NBX;
  long m0 = (long)by*128;
  int n0 = bx*BN;

  int arow[2], ach[2], aslot[2];
  #pragma unroll
  for (int j=0;j<2;j++){
    int idx = (wid*2+j)*64 + l;
    aslot[j] = idx*8;
    arow[j]  = ((idx>>6)<<4) | (idx & 15);
    ach[j]   = ((idx>>4) & 3)*8;
  }
  int brow[NF/2], bch[NF/2], bslot[NF/2];
  #pragma unroll
  for (int j=0;j<NF/2;j++){
    int idx = (wid*(NF/2)+j)*64 + l;
    bslot[j] = idx*8;
    brow[j]  = ((idx>>6)<<4) | (idx & 15);
    bch[j]   = ((idx>>4) & 3)*8;
  }

  f32x4 acc[4][NF];
  #pragma unroll
  for (int mf=0;mf<4;mf++)
    #pragma unroll
    for (int nf=0;nf<NF;nf++) acc[mf][nf] = (f32x4){0.f,0.f,0.f,0.f};

  int nt = K >> 5;
  #pragma unroll
  for (int j=0;j<2;j++)    gload16(A  + (m0+arow[j])*K + ach[j], Asb + aslot[j]);
  #pragma unroll
  for (int j=0;j<NF/2;j++) gload16(Bt + (long)(n0+brow[j])*K + bch[j], Bsb + bslot[j]);
  #pragma unroll
  for (int j=0;j<2;j++)    gload16(A  + (m0+arow[j])*K + 32 + ach[j], Asb + ABUF + aslot[j]);
  #pragma unroll
  for (int j=0;j<NF/2;j++) gload16(Bt + (long)(n0+brow[j])*K + 32 + bch[j], Bsb + BBUF + bslot[j]);

  int c0 = 0;
  for (int kt=0; kt<nt; kt++){
    if constexpr (NF==4) asm volatile("s_waitcnt vmcnt(4)" ::: "memory");
    else                 asm volatile("s_waitcnt vmcnt(3)" ::: "memory");
    __builtin_amdgcn_s_barrier();
    __builtin_amdgcn_sched_barrier(0);
    if (kt+2 < nt){
      int c2 = c0+2; if (c2>=3) c2-=3;
      int ko = (kt+2)*32;
      #pragma unroll
      for (int j=0;j<2;j++)    gload16(A  + (m0+arow[j])*K + ko + ach[j], Asb + c2*ABUF + aslot[j]);
      #pragma unroll
      for (int j=0;j<NF/2;j++) gload16(Bt + (long)(n0+brow[j])*K + ko + bch[j], Bsb + c2*BBUF + bslot[j]);
    }
    const u16* Ac = Asb + c0*ABUF;
    const u16* Bc = Bsb + c0*BBUF;
    bf16x8 af[4], bfv[NF];
    #pragma unroll
    for (int mf=0;mf<4;mf++) af[mf]  = *(const bf16x8*)(Ac + (((wr*4+mf)*4 + q)*16 + r)*8);
    #pragma unroll
    for (int nf=0;nf<NF;nf++) bfv[nf] = *(const bf16x8*)(Bc + (((wc*NF+nf)*4 + q)*16 + r)*8);
    #pragma unroll
    for (int mf=0;mf<4;mf++)
      #pragma unroll
      for (int nf=0;nf<NF;nf++)
        acc[mf][nf] = __builtin_amdgcn_mfma_f32_16x16x32_bf16(af[mf], bfv[nf], acc[mf][nf], 0,0,0);
    c0 = (c0+1==3) ? 0 : c0+1;
  }

  float s=0.f, ss=0.f;
  #pragma unroll
  for (int mf=0;mf<4;mf++)
    #pragma unroll
    for (int nf=0;nf<NF;nf++)
      #pragma unroll
      for (int j=0;j<4;j++){ float v = acc[mf][nf][j]; s += v; ss += v*v; }
  #pragma unroll
  for (int off=32; off>0; off>>=1){ s += __shfl_down(s,off,64); ss += __shfl_down(ss,off,64); }
  __shared__ float rs[4], rss[4];
  if (l==0){ rs[wid]=s; rss[wid]=ss; }
  __syncthreads();                 // all compute done -> SH reusable
  if (tid==0){
    int bc = (int)(m0 >> 7);
    int g = (bc/24)*4 + (bc%24)/6;
    atomicAdd(&raw[g],    rs[0]+rs[1]+rs[2]+rs[3]);
    atomicAdd(&raw[16+g], rss[0]+rss[1]+rss[2]+rss[3]);
  }

  if constexpr (STORE){
    #pragma unroll
    for (int mf=0;mf<4;mf++){
      int row = wr*64 + mf*16 + q*4;
      #pragma unroll
      for (int nf=0;nf<NF;nf++){
        int col = wc*(NF*16) + nf*16 + r;
        #pragma unroll
        for (int j=0;j<4;j++)
          SH[(row+j)*BNP + col] = f2b(acc[mf][nf][j]);
      }
    }
    __syncthreads();
    constexpr int RPT = BN/16;
    #pragma unroll
    for (int k=0;k<RPT;k++){
      int j = tid + k*256;
      int row = j / (BN/8), col8 = (j % (BN/8))*8;
      *(int4*)(C + (m0+row)*N + n0 + col8) = *(const int4*)(SH + row*BNP + col8);
    }
  }
}

// ---------------- attention: att[4][6] (fp32) ----------------
__global__ void attention_kernel(const float* __restrict__ c, const float* __restrict__ wq,
                                 const float* __restrict__ bq, const float* __restrict__ keys,
                                 float* __restrict__ att){
  __shared__ float q[4][32];
  __shared__ float s[4][6];
  int t = threadIdx.x;
  if (t < 128){
    int b = t >> 5, k = t & 31;
    float a = bq[k];
    for (int j=0;j<32;j++) a += c[b*32+j] * wq[k*32+j];
    q[b][k] = a;
  }
  __syncthreads();
  if (t < 24){
    int b = t/6, n = t%6;
    float a = 0.f;
    for (int k=0;k<32;k++) a += q[b][k]*keys[k*6+n];
    s[b][n] = a * 0.17677669529663689f;
  }
  __syncthreads();
  if (t < 4){
    float mx = -1e30f;
    for (int n=0;n<6;n++) mx = fmaxf(mx, s[t][n]);
    float e[6], sm=0.f;
    for (int n=0;n<6;n++){ e[n]=expf(s[t][n]-mx); sm+=e[n]; }
    for (int n=0;n<6;n++) att[t*6+n] = e[n]/sm;
  }
}

// ---------------- final: out(fp32) = x_ + sum_n relu(gn2(h2))[...,n]*att[b,n] (inline GN) ----------------
__global__ __launch_bounds__(256)
void final_mix(const u16* __restrict__ h2, const u16* __restrict__ xr,
               const float* __restrict__ raw, const float* __restrict__ gw,
               const float* __restrict__ gb, float invN,
               const float* __restrict__ att, float* __restrict__ out){
  __shared__ float s_sc, s_off, s_att[6];
  int bc0 = blockIdx.x / 64;                // block spans single (b,c)
  int c  = bc0 % 24, b = bc0 / 24;
  if (threadIdx.x == 0){
    int g = b*4 + c/6;
    float m = raw[g]*invN;
    float var = raw[16+g]*invN - m*m;
    float is = rsqrtf(var + EPS);
    float sc = is*gw[c];
    s_sc = sc;
    s_off = gb[c] - m*sc;
  }
  if (threadIdx.x < 6) s_att[threadIdx.x] = att[b*6+threadIdx.x];
  __syncthreads();
  float sc = s_sc, off = s_off;
  float a[6];
  #pragma unroll
  for (int n=0;n<6;n++) a[n] = s_att[n];

  int gid = blockIdx.x*256 + threadIdx.x;
  int fq = gid & 127;
  int t  = (gid >> 7) & 127;
  int bc = gid >> 14;

  long hbase = (((long)bc*Tn + t))*3072 + (long)fq*24;
  union { int4 v[3]; u16 u[24]; } hv;
  const int4* hp = (const int4*)(h2 + hbase);
  hv.v[0]=hp[0]; hv.v[1]=hp[1]; hv.v[2]=hp[2];

  long xbase = (((long)bc*Tn + t))*Fn + (long)fq*4;
  union { unsigned long long q; u16 u[4]; } xv;
  xv.q = *(const unsigned long long*)(xr + xbase);

  float4 ov;
  float* op = &ov.x;
  #pragma unroll
  for (int j=0;j<4;j++){
    float accv = b2f(xv.u[j]);
    #pragma unroll
    for (int n=0;n<6;n++){
      float hvf = b2f(hv.u[j*6+n])*sc + off;
      hvf = hvf > 0.f ? hvf : 0.f;
      accv += hvf * a[n];
    }
    op[j] = accv;
  }
  *(float4*)(out + xbase) = ov;
}

extern "C" void kernel_launch(void* const* d_in, const int* in_sizes, int n_in,
                              void* d_out, int out_size, void* d_ws, size_t ws_size,
                              hipStream_t stream){
  const float* x   = (const float*)d_in[0];
  const float* c   = (const float*)d_in[1];
  const float* cw0 = (const float*)d_in[2];  const float* cb0 = (const float*)d_in[3];
  const float* gw0 = (const float*)d_in[4];  const float* gb0 = (const float*)d_in[5];
  const float* cw1 = (const float*)d_in[6];  const float* cb1 = (const float*)d_in[7];
  const float* gw1 = (const float*)d_in[8];  const float* gb1 = (const float*)d_in[9];
  const float* cw2 = (const float*)d_in[10]; const float* cb2 = (const float*)d_in[11];
  const float* gw2 = (const float*)d_in[12]; const float* gb2 = (const float*)d_in[13];
  const float* tw1 = (const float*)d_in[14]; const float* tg1w= (const float*)d_in[15]; const float* tg1b=(const float*)d_in[16];
  const float* tw2 = (const float*)d_in[17]; const float* tg2w= (const float*)d_in[18]; const float* tg2b=(const float*)d_in[19];
  const float* wqp = (const float*)d_in[20]; const float* bqp = (const float*)d_in[21]; const float* keys=(const float*)d_in[22];

  char* ws = (char*)d_ws;
  u16*   xr     = (u16*)(ws + 0);               // 12,582,912 B  [12288,512] bf16 CHW
  u16*   h1     = (u16*)(ws + 12582912);        //  4,718,592 B  [12288,192]
  u16*   tw1b   = (u16*)(ws + 17301504);        //    196,608 B
  u16*   tw2b   = (u16*)(ws + 17498112);        //  1,179,648 B
  float* stats5 = (float*)(ws + 18677760);      //        128 B
  float* att    = (float*)(ws + 18678656);      //        128 B
  // ---- h2 span (reused during conv phase) ----
  u16*   h2     = (u16*)(ws + 18680832);        // 75,497,472 B  [12288,3072]
  u16*   Y      = (u16*)(ws + 18680832);        // 12,582,912 B  NHWC conv out [4,128,512,24]
  u16*   b72p   = (u16*)(ws + 31263744);        // 38,488,320 B  NHWC padded [4,130,514,72]
  u16*   xc24   = (u16*)(ws + 69752064);        // 12,829,440 B (+256 slack) NHWC padded [4,130,514,24]
  float* stats14= (float*)(ws + 82581760);      //        512 B
  u16*   wr0    = (u16*)(ws + 82585344);        //     18,432 B
  u16*   wr1    = (u16*)(ws + 82603776);        //     36,864 B
  u16*   wr2    = (u16*)(ws + 82640640);        //     43,008 B

  border_zero<<<dim3(32,4),256,0,stream>>>(b72p, 72);
  border_zero<<<dim3(16,4),256,0,stream>>>(xc24, 24);
  zero_stats2<<<1,256,0,stream>>>(stats14, stats5);

  prep_wr<<<36,256,0,stream>>>(cw0, wr0, 24, 24, 0, 96);
  prep_wr<<<72,256,0,stream>>>(cw1, wr1, 48, 72, 24, 192);
  prep_wr<<<84,256,0,stream>>>(cw2, wr2, 72, 72, 0, 224);
  cvt_f2b<<<96,256,0,stream>>>(tw1, tw1b);
  cvt_f2b<<<576,256,0,stream>>>(tw2, tw2b);
  copy_x2<<<512,256,0,stream>>>(x, b72p, xc24);
  attention_kernel<<<1,128,0,stream>>>(c, wqp, bqp, keys, att);

  // ---- conv block 0 ----
  conv_mfma<96,24><<<512,256,0,stream>>>(xc24, 0, wr0, cb0, Y, stats14+0);
  norm_relu_nhwc<<<3072,256,0,stream>>>(Y, b72p, 24, stats14+0, gw0, gb0, 1.f/393216.f);

  // ---- conv block 1 ----
  conv_mfma<192,72><<<512,256,0,stream>>>(b72p, 24, wr1, cb1, Y, stats14+32);
  norm_relu_nhwc<<<3072,256,0,stream>>>(Y, b72p, 0, stats14+32, gw1, gb1, 1.f/393216.f);

  // ---- conv block 2 -> xr (CHW) ----
  conv_mfma<224,72><<<512,256,0,stream>>>(b72p, 0, wr2, cb2, Y, stats14+64);
  norm_relu_chw<<<512,256,0,stream>>>(Y, xr, stats14+64, gw2, gb2, 1.f/393216.f);

  // ---- TDF: gemm1 (12288x192x512) + GN + relu ----
  gemm_lds<2,true><<<288,256,0,stream>>>(xr, tw1b, h1, 192, 512, 3, stats14+96);
  norm_chw<<<1152,256,0,stream>>>(h1, stats14+96, tg1w, tg1b, 1.f/147456.f);

  // ---- TDF: gemm2 (12288x3072x192), tile 128x128 ----
  gemm_lds<4,true><<<2304,256,0,stream>>>(h1, tw2b, h2, 3072, 192, 24, stats5);

  // ---- final mix (inline GN2 params) ----
  final_mix<<<6144,256,0,stream>>>(h2, xr, stats5, tg2w, tg2b, 1.f/2359296.f, att, (float*)d_out);
}